// Round 22
// baseline (71.259 us; speedup 1.0000x reference)
//
#include <hip/hip_runtime.h>
#include <hip/hip_bf16.h>

// Sizes fixed by the reference problem.
#define B_N   4096
#define D_N   1024
#define P_N   64
#define C0_N  16
#define C1_N  32
#define NC_N  48    // C0 + C1 concatenated

// fused parent kernel geometry
#define PR    16     // rows per block; 256 blocks = 1/CU, all CUs busy
#define PKC   8      // K chunks
#define PDK   128    // chunk depth

// child GEMM K-split — KC2 MUST stay 8 (r14/r16: 16 writers/row -> ~30x HBM amp).
#define KC2   8
#define DKC2  128
#define TRC   64     // child MFMA row tile

// Tie physics: fp32 softmax probs can only tie when the true logit gap is
// <~2e-7. With the 3-pass bf16-split parent GEMM the logit error is ~2-3e-8,
// so tau=1e-6 keeps ~25x margin; ~15-30 suspect rows total.
#define GAP_TAU 1e-6f
#define NEG_INF (-3.402823466e38f)

// Lessons (r10-r21): no grid.sync; no per-block device fences; no <500-block
// kernels UNLESS every CU holds exactly one uniform-work block (r22: 256
// blocks, 1/CU, no load imbalance); child KC2=8 only; single-writer 256B
// chunks; counts zeroed by a dedicated memset (racing block-0-zeroing
// against same-kernel routing atomics would be dispatch-timing-dependent).
// r22: parent K-split + partials + route kernel replaced by ONE full-K
// fused kernel (MFMA bf16-split, register accumulator across chunks).

typedef __attribute__((ext_vector_type(8))) short short8v;
typedef __attribute__((ext_vector_type(4))) float f32x4;

static __device__ __forceinline__ unsigned short f2bf(float f) {
    union { float f; unsigned u; } v; v.f = f;
    const unsigned r = v.u + 0x7FFF + ((v.u >> 16) & 1);   // RNE
    return (unsigned short)(r >> 16);
}

// split f into hi (bf16 RNE) and lo (bf16 of exact residual)
static __device__ __forceinline__ void split_bf(float f,
                                                unsigned short& h,
                                                unsigned short& l) {
    h = f2bf(f);
    union { unsigned u; float f; } hv; hv.u = (unsigned)h << 16;
    l = f2bf(f - hv.f);
}

// ===========================================================================
// P: fused parent — full-K MFMA logits + route + fixup + c0/c1 zeroing.
// 256 blocks x 256 threads; block = 16 rows x 64 parents x K=1024.
// Per chunk (K=128): stage+split x (16x128) and pw (64x128) to LDS k-major;
// wave wv computes its 16-parent n-tile: acc = mfma(xh,wh)+mfma(xl,wh)+
// mfma(xh,wl), fp32 acc HELD ACROSS CHUNKS. Then logits -> LDS (+pb),
// per-wave top-2 routing (4 rows/wave), near-ties -> LDS queue, block-
// cooperative f64 softmax-emulation fixup (first-index argmax on fp32-
// quantized probs). Also zeroes this block's 768-float c0/c1 slice.
// LDS ~45KB. No partials buffer, no separate route kernel.
// ===========================================================================
__global__ __launch_bounds__(256, 1)
void hc_parent_fused(const float* __restrict__ x,
                     const float* __restrict__ pw,
                     const float* __restrict__ pb,
                     float* __restrict__ out_logits,
                     float* __restrict__ out_cz,      // = out_c0 (contig c0|c1)
                     int* __restrict__ counts,
                     int* __restrict__ lists) {
    __shared__ unsigned short xh[16][PR][8], xl[16][PR][8];    // [kq][row][8]
    __shared__ unsigned short wh[16][P_N][8], wl[16][P_N][8];  // [kq][par][8]
    __shared__ float  llds[PR][68];
    __shared__ double ld[P_N];
    __shared__ int    sq[PR];
    __shared__ int    sqn;

    const int tid = threadIdx.x;
    const int r0  = blockIdx.x * PR;

    if (tid == 0) sqn = 0;
    // zero this block's slice of the child outputs (16 rows x 48 = 192 f4)
    if (tid < 192)
        ((float4*)(out_cz + (size_t)blockIdx.x * (PR * NC_N)))[tid] =
            make_float4(0.f, 0.f, 0.f, 0.f);

    const int lane = tid & 63;
    const int wv   = tid >> 6;     // wave 0..3 -> parents [wv*16, wv*16+16)
    const int lr   = lane & 15;
    const int lg   = lane >> 4;

    f32x4 acc = {0.f, 0.f, 0.f, 0.f};

    for (int kc = 0; kc < PKC; ++kc) {
        const int d0 = kc * PDK;
        __syncthreads();               // protect previous chunk's LDS reads
        // stage + split x: 16 rows x 128 floats = 512 float4, 2 per thread
        #pragma unroll
        for (int k = 0; k < 2; ++k) {
            const int f = tid + 256 * k, r = f >> 5, c4 = (f & 31) * 4;
            const float4 v = *(const float4*)&x[(size_t)(r0 + r) * D_N + d0 + c4];
            unsigned short* dh = &xh[c4 >> 3][r][c4 & 4];
            unsigned short* dl = &xl[c4 >> 3][r][c4 & 4];
            split_bf(v.x, dh[0], dl[0]); split_bf(v.y, dh[1], dl[1]);
            split_bf(v.z, dh[2], dl[2]); split_bf(v.w, dh[3], dl[3]);
        }
        // stage + split pw chunk: 64 parents x 128 floats = 2048 float4
        #pragma unroll
        for (int k = 0; k < 8; ++k) {
            const int f = tid + 256 * k, r = f >> 5, c4 = (f & 31) * 4;
            const float4 v = *(const float4*)&pw[(size_t)r * D_N + d0 + c4];
            unsigned short* dh = &wh[c4 >> 3][r][c4 & 4];
            unsigned short* dl = &wl[c4 >> 3][r][c4 & 4];
            split_bf(v.x, dh[0], dl[0]); split_bf(v.y, dh[1], dl[1]);
            split_bf(v.z, dh[2], dl[2]); split_bf(v.w, dh[3], dl[3]);
        }
        __syncthreads();

        #pragma unroll
        for (int ks = 0; ks < 4; ++ks) {
            const int kq = ks * 4 + lg;
            const short8v ah = *(const short8v*)&xh[kq][lr][0];
            const short8v al = *(const short8v*)&xl[kq][lr][0];
            const short8v bh = *(const short8v*)&wh[kq][wv * 16 + lr][0];
            const short8v bl = *(const short8v*)&wl[kq][wv * 16 + lr][0];
            acc = __builtin_amdgcn_mfma_f32_16x16x32_bf16(ah, bh, acc, 0, 0, 0);
            acc = __builtin_amdgcn_mfma_f32_16x16x32_bf16(al, bh, acc, 0, 0, 0);
            acc = __builtin_amdgcn_mfma_f32_16x16x32_bf16(ah, bl, acc, 0, 0, 0);
        }
    }
    __syncthreads();
    // D layout (m89, r20/21-validated): x-row = lg*4+reg, parent = wv*16+lr
    #pragma unroll
    for (int reg = 0; reg < 4; ++reg)
        llds[lg * 4 + reg][wv * 16 + lr] = acc[reg];
    __syncthreads();

    // ---- route: wave wv handles rows wv*4 .. wv*4+3 ----
    const int p = lane;
    #pragma unroll
    for (int rq = 0; rq < 4; ++rq) {
        const int rloc = wv * 4 + rq;
        const int row  = r0 + rloc;
        const float l  = llds[rloc][p] + pb[p];
        out_logits[(size_t)row * P_N + p] = l;

        float m1 = l; int i1 = p; float m2 = NEG_INF;
        #pragma unroll
        for (int off = 32; off > 0; off >>= 1) {
            const float om1 = __shfl_xor(m1, off);
            const int   oi1 = __shfl_xor(i1, off);
            const float om2 = __shfl_xor(m2, off);
            if (om1 > m1 || (om1 == m1 && oi1 < i1)) {
                m2 = fmaxf(m1, om2); m1 = om1; i1 = oi1;
            } else m2 = fmaxf(m2, om1);
        }
        if (p == 0) {
            if (m1 - m2 > GAP_TAU) {
                const int pos = atomicAdd(&counts[i1], 1);
                lists[i1 * B_N + pos] = row;
            } else {
                const int q = atomicAdd(&sqn, 1);
                sq[q] = row;
            }
        }
    }
    __syncthreads();

    const int nq = sqn;
    if (nq == 0) return;    // uniform

    // ---- block-cooperative f64 fixup (~26 suspect rows chip-wide) ----
    for (int qi = 0; qi < nq; ++qi) {
        const int srow = sq[qi];
        const float* xr = &x[(size_t)srow * D_N + p * 16];
        float4 xv[4];
        #pragma unroll
        for (int k = 0; k < 4; ++k) xv[k] = *(const float4*)&xr[k * 4];

        #pragma unroll 2
        for (int pass = 0; pass < 16; ++pass) {
            const int pp = wv * 16 + pass;
            const float* wr = &pw[(size_t)pp * D_N + p * 16];
            double a0 = 0.0, a1 = 0.0, a2 = 0.0, a3 = 0.0;
            #pragma unroll
            for (int k = 0; k < 4; ++k) {
                const float4 wv2 = *(const float4*)&wr[k * 4];
                a0 = fma((double)wv2.x, (double)xv[k].x, a0);
                a1 = fma((double)wv2.y, (double)xv[k].y, a1);
                a2 = fma((double)wv2.z, (double)xv[k].z, a2);
                a3 = fma((double)wv2.w, (double)xv[k].w, a3);
            }
            double a = (a0 + a1) + (a2 + a3);
            #pragma unroll
            for (int off = 32; off > 0; off >>= 1) a += __shfl_xor(a, off);
            if (p == 0) ld[pp] = a;
        }
        __syncthreads();

        if (wv == 0) {
            const double accv = (double)pb[p] + ld[p];
            const float  l32  = (float)accv;
            float m = l32;
            #pragma unroll
            for (int off = 32; off > 0; off >>= 1)
                m = fmaxf(m, __shfl_xor(m, off));
            const float e = (float)exp((double)(l32 - m));  // correctly-rounded
            double es = (double)e;
            #pragma unroll
            for (int off = 32; off > 0; off >>= 1) es += __shfl_xor(es, off);
            es = __shfl(es, 0);
            const float s    = (float)es;
            const float prob = e / s;    // IEEE f32 divide: ties survive
            float pm = prob; int pi = p;
            #pragma unroll
            for (int off = 32; off > 0; off >>= 1) {
                const float opm = __shfl_xor(pm, off);
                const int   opi = __shfl_xor(pi, off);
                if (opm > pm || (opm == pm && opi < pi)) { pm = opm; pi = opi; }
            }
            if (p == 0) {
                const int pos = atomicAdd(&counts[pi], 1);
                lists[pi * B_N + pos] = srow;
            }
        }
        __syncthreads();
    }
}

// ===========================================================================
// C: child GEMM via bf16 MFMA (proven r20/21). Tile 64 rows x 48 outs x
// K=128. LDS k-major [16][row][8] bf16, lane-contiguous fragments.
// atomicAdd epilogue onto P-zeroed outputs, bias at kc==0. UNCHANGED.
// ===========================================================================
__global__ __launch_bounds__(256, 5)
void hc_child_mfma(const float* __restrict__ x,
                   const float* __restrict__ w0,
                   const float* __restrict__ w1,
                   const float* __restrict__ b0,
                   const float* __restrict__ b1,
                   const int* __restrict__ counts,
                   const int* __restrict__ lists,
                   float* __restrict__ out_c0,
                   float* __restrict__ out_c1) {
    const int c  = blockIdx.x;
    const int kc = blockIdx.y;
    const int n  = counts[c];
    const int t0 = blockIdx.z * TRC;
    if (t0 >= n) return;
    const int m  = min(TRC, n - t0);
    const int d0 = kc * DKC2;

    __shared__ int            rl[TRC];
    __shared__ unsigned short xs[16][TRC][8];    // [kchunk][row][8k] bf16
    __shared__ unsigned short ws[16][NC_N][8];   // [kchunk][out][8k] bf16

    const int tid = threadIdx.x;
    if (tid < TRC)
        rl[tid] = lists[c * B_N + t0 + (tid < m ? tid : 0)];

    // stage weights: 48 rows x 128 floats
    #pragma unroll
    for (int k = 0; k < 6; ++k) {
        const int f = tid + 256 * k, j = f >> 5, c4 = (f & 31) * 4;
        const float* src = (j < C0_N)
            ? &w0[((size_t)c * C0_N + j) * D_N + d0 + c4]
            : &w1[((size_t)c * C1_N + (j - C0_N)) * D_N + d0 + c4];
        const float4 v = *(const float4*)src;
        unsigned short* dst = &ws[c4 >> 3][j][c4 & 4];
        dst[0] = f2bf(v.x); dst[1] = f2bf(v.y);
        dst[2] = f2bf(v.z); dst[3] = f2bf(v.w);
    }
    __syncthreads();   // rl visible before gather
    // stage gathered x rows: 64 rows x 128 floats
    #pragma unroll
    for (int k = 0; k < 8; ++k) {
        const int f = tid + 256 * k, r = f >> 5, c4 = (f & 31) * 4;
        const float4 v = *(const float4*)&x[(size_t)rl[r] * D_N + d0 + c4];
        unsigned short* dst = &xs[c4 >> 3][r][c4 & 4];
        dst[0] = f2bf(v.x); dst[1] = f2bf(v.y);
        dst[2] = f2bf(v.z); dst[3] = f2bf(v.w);
    }
    __syncthreads();

    const int lane = tid & 63;
    const int wv   = tid >> 6;
    const int lr   = lane & 15;
    const int lg   = lane >> 4;

    f32x4 acc0 = {0.f, 0.f, 0.f, 0.f};
    f32x4 acc1 = {0.f, 0.f, 0.f, 0.f};
    f32x4 acc2 = {0.f, 0.f, 0.f, 0.f};
    #pragma unroll
    for (int ks = 0; ks < 4; ++ks) {
        const int kq = ks * 4 + lg;
        const short8v a  = *(const short8v*)&xs[kq][wv * 16 + lr][0];
        const short8v bA = *(const short8v*)&ws[kq][lr][0];
        const short8v bB = *(const short8v*)&ws[kq][16 + lr][0];
        const short8v bC = *(const short8v*)&ws[kq][32 + lr][0];
        acc0 = __builtin_amdgcn_mfma_f32_16x16x32_bf16(a, bA, acc0, 0, 0, 0);
        acc1 = __builtin_amdgcn_mfma_f32_16x16x32_bf16(a, bB, acc1, 0, 0, 0);
        acc2 = __builtin_amdgcn_mfma_f32_16x16x32_bf16(a, bC, acc2, 0, 0, 0);
    }

    #pragma unroll
    for (int reg = 0; reg < 4; ++reg) {
        const int rr = wv * 16 + lg * 4 + reg;
        if (rr < m) {
            const int row = rl[rr];
            #pragma unroll
            for (int nt = 0; nt < 3; ++nt) {
                const int jj = nt * 16 + lr;
                float v = (nt == 0) ? acc0[reg] : (nt == 1) ? acc1[reg] : acc2[reg];
                if (kc == 0)
                    v += (jj < C0_N) ? b0[c * C0_N + jj]
                                     : b1[c * C1_N + (jj - C0_N)];
                if (jj < C0_N)
                    atomicAdd(&out_c0[(size_t)row * C0_N + jj], v);
                else
                    atomicAdd(&out_c1[(size_t)row * C1_N + (jj - C0_N)], v);
            }
        }
    }
}

// ---------------------------------------------------------------------------
extern "C" void kernel_launch(void* const* d_in, const int* in_sizes, int n_in,
                              void* d_out, int out_size, void* d_ws, size_t ws_size,
                              hipStream_t stream) {
    const float* x  = (const float*)d_in[0];
    const float* pw = (const float*)d_in[1];
    const float* pb = (const float*)d_in[2];
    const float* w0 = (const float*)d_in[3];
    const float* b0 = (const float*)d_in[4];
    const float* w1 = (const float*)d_in[5];
    const float* b1 = (const float*)d_in[6];

    float* out_logits = (float*)d_out;                       // [4096][64]
    float* out_c0     = out_logits + (size_t)B_N * P_N;      // [4096][16]
    float* out_c1     = out_c0     + (size_t)B_N * C0_N;     // [4096][32]

    // ws: [counts 64] [lists 64*4096] — no partials buffer anymore (~1MB)
    int* counts = (int*)d_ws;
    int* lists  = counts + 64;

    hipMemsetAsync(counts, 0, P_N * sizeof(int), stream);

    hc_parent_fused<<<B_N / PR, 256, 0, stream>>>(
        x, pw, pb, out_logits, out_c0, counts, lists);

    hc_child_mfma<<<dim3(P_N, KC2, 3), 256, 0, stream>>>(
        x, w0, w1, b0, b1, counts, lists, out_c0, out_c1);
}

// Round 23
// 61.558 us; speedup vs baseline: 1.1576x; 1.1576x over previous
//
#include <hip/hip_runtime.h>
#include <hip/hip_bf16.h>

// Sizes fixed by the reference problem.
#define B_N   4096
#define D_N   1024
#define P_N   64
#define C0_N  16
#define C1_N  32
#define NC_N  48    // C0 + C1 concatenated

// fused parent kernel geometry (r23): 256 blocks x 512 threads (8 waves)
#define PR    16     // rows per block
#define PKC   8      // K chunks
#define PDK   128    // chunk depth

// child GEMM K-split — KC2 MUST stay 8 (r14/r16: 16 writers/row -> ~30x HBM amp).
#define KC2   8
#define DKC2  128
#define TRC   64     // child MFMA row tile

// Tie physics: fp32 softmax probs can only tie when the true logit gap is
// <~2e-7. With the 3-pass bf16-split parent GEMM the logit error is ~2-3e-8,
// so tau=1e-6 keeps ~25x margin; ~15-30 suspect rows total.
#define GAP_TAU 1e-6f
#define NEG_INF (-3.402823466e38f)

// Lessons (r10-r22): no grid.sync; no per-block device fences; enough waves
// per CU (r22: 4 waves/CU fused parent = 62us latency-bound); LDS kq-plane
// strides must not be ≡0 mod 128B (r22: 4.59M bank conflicts); child KC2=8
// only; single-writer 256B chunks; minimize dispatches.

typedef __attribute__((ext_vector_type(8))) short short8v;
typedef __attribute__((ext_vector_type(4))) float f32x4;

static __device__ __forceinline__ unsigned f2bf(float f) {
    union { float f; unsigned u; } v; v.f = f;
    return (v.u + 0x7FFF + ((v.u >> 16) & 1)) >> 16;   // RNE, low 16 valid
}
// split float4 into packed-hi (2x uint) and packed-lo residual (2x uint)
static __device__ __forceinline__ void split4(float4 v, uint2& hp, uint2& lp) {
    const unsigned hx = f2bf(v.x), hy = f2bf(v.y);
    const unsigned hz = f2bf(v.z), hw = f2bf(v.w);
    union { unsigned u; float f; } t;
    float rx, ry, rz, rw;
    t.u = hx << 16; rx = v.x - t.f;
    t.u = hy << 16; ry = v.y - t.f;
    t.u = hz << 16; rz = v.z - t.f;
    t.u = hw << 16; rw = v.w - t.f;
    hp.x = hx | (hy << 16);           hp.y = hz | (hw << 16);
    lp.x = f2bf(rx) | (f2bf(ry) << 16); lp.y = f2bf(rz) | (f2bf(rw) << 16);
}

// ===========================================================================
// P: fused parent — full-K MFMA logits + route + fixup + c0/c1 zeroing.
// 256 blocks x 512 threads (8 waves); block = 16 rows x 64 parents x K=1024.
// Wave wv: parent tile pt=wv&3, k-half kh=wv>>2 (two fp32 accs per (row,par),
// summed via llds, deterministic). LDS padded: xh/xl [16][17][8] (+4 banks/
// plane), wh/wl [16][67][8] (+12 banks/plane) -> staging writes <=2-way.
// After GEMM: logits->llds(+pb), 8 waves route 2 rows each (top-2, tau bin),
// near-ties -> LDS queue -> block-cooperative f64 softmax-emulation fixup
// (8 waves x 8 parent-passes; first-index argmax on fp32-quantized probs).
// Also zeroes this block's 768-float c0/c1 slice. counts zeroed by memset.
// ===========================================================================
__global__ __launch_bounds__(512, 2)
void hc_parent_fused(const float* __restrict__ x,
                     const float* __restrict__ pw,
                     const float* __restrict__ pb,
                     float* __restrict__ out_logits,
                     float* __restrict__ out_cz,      // = out_c0 (contig c0|c1)
                     int* __restrict__ counts,
                     int* __restrict__ lists) {
    __shared__ unsigned short xh[16][17][8], xl[16][17][8];
    __shared__ unsigned short wh[16][67][8], wl[16][67][8];
    __shared__ float  llds[PR][68];
    __shared__ double ld[P_N];
    __shared__ int    sq[PR];
    __shared__ int    sqn;

    const int tid = threadIdx.x;
    const int r0  = blockIdx.x * PR;

    if (tid == 0) sqn = 0;
    // zero this block's slice of the child outputs (16 rows x 48 = 192 f4)
    if (tid < 192)
        ((float4*)(out_cz + (size_t)blockIdx.x * (PR * NC_N)))[tid] =
            make_float4(0.f, 0.f, 0.f, 0.f);

    const int lane = tid & 63;
    const int wv   = tid >> 6;     // 0..7
    const int lr   = lane & 15;
    const int lg   = lane >> 4;
    const int pt   = wv & 3;       // parent tile
    const int kh   = wv >> 2;      // k-half of each chunk

    f32x4 acc = {0.f, 0.f, 0.f, 0.f};

    for (int kc = 0; kc < PKC; ++kc) {
        const int d0 = kc * PDK;
        __syncthreads();               // protect previous chunk's LDS reads
        // stage + split x: 16 rows x 128 floats = 512 float4, 1 per thread
        {
            const int r = tid >> 5, c4 = (tid & 31) * 4;
            const float4 v = *(const float4*)&x[(size_t)(r0 + r) * D_N + d0 + c4];
            uint2 hp, lp; split4(v, hp, lp);
            *(uint2*)&xh[c4 >> 3][r][c4 & 4] = hp;
            *(uint2*)&xl[c4 >> 3][r][c4 & 4] = lp;
        }
        // stage + split pw chunk: 64 parents x 128 floats = 2048 f4, 4/thread
        #pragma unroll
        for (int k = 0; k < 4; ++k) {
            const int f = tid + 512 * k, r = f >> 5, c4 = (f & 31) * 4;
            const float4 v = *(const float4*)&pw[(size_t)r * D_N + d0 + c4];
            uint2 hp, lp; split4(v, hp, lp);
            *(uint2*)&wh[c4 >> 3][r][c4 & 4] = hp;
            *(uint2*)&wl[c4 >> 3][r][c4 & 4] = lp;
        }
        __syncthreads();

        #pragma unroll
        for (int ks = 0; ks < 2; ++ks) {
            const int kq = kh * 8 + ks * 4 + lg;
            const short8v ah = *(const short8v*)&xh[kq][lr][0];
            const short8v al = *(const short8v*)&xl[kq][lr][0];
            const short8v bh = *(const short8v*)&wh[kq][pt * 16 + lr][0];
            const short8v bl = *(const short8v*)&wl[kq][pt * 16 + lr][0];
            acc = __builtin_amdgcn_mfma_f32_16x16x32_bf16(ah, bh, acc, 0, 0, 0);
            acc = __builtin_amdgcn_mfma_f32_16x16x32_bf16(al, bh, acc, 0, 0, 0);
            acc = __builtin_amdgcn_mfma_f32_16x16x32_bf16(ah, bl, acc, 0, 0, 0);
        }
    }
    __syncthreads();
    // combine k-halves: lower waves store, upper waves add (deterministic)
    // D layout (m89-validated): x-row = lg*4+reg, parent = pt*16+lr
    if (kh == 0) {
        #pragma unroll
        for (int reg = 0; reg < 4; ++reg)
            llds[lg * 4 + reg][pt * 16 + lr] = acc[reg];
    }
    __syncthreads();
    if (kh == 1) {
        #pragma unroll
        for (int reg = 0; reg < 4; ++reg)
            llds[lg * 4 + reg][pt * 16 + lr] += acc[reg];
    }
    __syncthreads();

    // ---- route: wave wv handles rows wv*2, wv*2+1 ----
    const int p = lane;
    #pragma unroll
    for (int rq = 0; rq < 2; ++rq) {
        const int rloc = wv * 2 + rq;
        const int row  = r0 + rloc;
        const float l  = llds[rloc][p] + pb[p];
        out_logits[(size_t)row * P_N + p] = l;

        float m1 = l; int i1 = p; float m2 = NEG_INF;
        #pragma unroll
        for (int off = 32; off > 0; off >>= 1) {
            const float om1 = __shfl_xor(m1, off);
            const int   oi1 = __shfl_xor(i1, off);
            const float om2 = __shfl_xor(m2, off);
            if (om1 > m1 || (om1 == m1 && oi1 < i1)) {
                m2 = fmaxf(m1, om2); m1 = om1; i1 = oi1;
            } else m2 = fmaxf(m2, om1);
        }
        if (p == 0) {
            if (m1 - m2 > GAP_TAU) {
                const int pos = atomicAdd(&counts[i1], 1);
                lists[i1 * B_N + pos] = row;
            } else {
                const int q = atomicAdd(&sqn, 1);
                sq[q] = row;
            }
        }
    }
    __syncthreads();

    const int nq = sqn;
    if (nq == 0) return;    // uniform across the block

    // ---- block-cooperative f64 fixup (~26 suspect rows chip-wide) ----
    for (int qi = 0; qi < nq; ++qi) {
        const int srow = sq[qi];
        const float* xr = &x[(size_t)srow * D_N + p * 16];
        float4 xv[4];
        #pragma unroll
        for (int k = 0; k < 4; ++k) xv[k] = *(const float4*)&xr[k * 4];

        #pragma unroll 2
        for (int pass = 0; pass < 8; ++pass) {
            const int pp = wv * 8 + pass;
            const float* wr = &pw[(size_t)pp * D_N + p * 16];
            double a0 = 0.0, a1 = 0.0, a2 = 0.0, a3 = 0.0;
            #pragma unroll
            for (int k = 0; k < 4; ++k) {
                const float4 wv2 = *(const float4*)&wr[k * 4];
                a0 = fma((double)wv2.x, (double)xv[k].x, a0);
                a1 = fma((double)wv2.y, (double)xv[k].y, a1);
                a2 = fma((double)wv2.z, (double)xv[k].z, a2);
                a3 = fma((double)wv2.w, (double)xv[k].w, a3);
            }
            double a = (a0 + a1) + (a2 + a3);
            #pragma unroll
            for (int off = 32; off > 0; off >>= 1) a += __shfl_xor(a, off);
            if (p == 0) ld[pp] = a;
        }
        __syncthreads();

        if (wv == 0) {
            const double accv = (double)pb[p] + ld[p];
            const float  l32  = (float)accv;
            float m = l32;
            #pragma unroll
            for (int off = 32; off > 0; off >>= 1)
                m = fmaxf(m, __shfl_xor(m, off));
            const float e = (float)exp((double)(l32 - m));  // correctly-rounded
            double es = (double)e;
            #pragma unroll
            for (int off = 32; off > 0; off >>= 1) es += __shfl_xor(es, off);
            es = __shfl(es, 0);
            const float s    = (float)es;
            const float prob = e / s;    // IEEE f32 divide: ties survive
            float pm = prob; int pi = p;
            #pragma unroll
            for (int off = 32; off > 0; off >>= 1) {
                const float opm = __shfl_xor(pm, off);
                const int   opi = __shfl_xor(pi, off);
                if (opm > pm || (opm == pm && opi < pi)) { pm = opm; pi = opi; }
            }
            if (p == 0) {
                const int pos = atomicAdd(&counts[pi], 1);
                lists[pi * B_N + pos] = srow;
            }
        }
        __syncthreads();
    }
}

// ===========================================================================
// C: child GEMM via bf16 MFMA (proven r20/21). Tile 64 rows x 48 outs x
// K=128. LDS k-major [16][row][8] bf16, lane-contiguous fragments.
// atomicAdd epilogue onto P-zeroed outputs, bias at kc==0. UNCHANGED.
// ===========================================================================
__global__ __launch_bounds__(256, 5)
void hc_child_mfma(const float* __restrict__ x,
                   const float* __restrict__ w0,
                   const float* __restrict__ w1,
                   const float* __restrict__ b0,
                   const float* __restrict__ b1,
                   const int* __restrict__ counts,
                   const int* __restrict__ lists,
                   float* __restrict__ out_c0,
                   float* __restrict__ out_c1) {
    const int c  = blockIdx.x;
    const int kc = blockIdx.y;
    const int n  = counts[c];
    const int t0 = blockIdx.z * TRC;
    if (t0 >= n) return;
    const int m  = min(TRC, n - t0);
    const int d0 = kc * DKC2;

    __shared__ int            rl[TRC];
    __shared__ unsigned short xs[16][TRC][8];    // [kchunk][row][8k] bf16
    __shared__ unsigned short ws[16][NC_N][8];   // [kchunk][out][8k] bf16

    const int tid = threadIdx.x;
    if (tid < TRC)
        rl[tid] = lists[c * B_N + t0 + (tid < m ? tid : 0)];

    // stage weights: 48 rows x 128 floats
    #pragma unroll
    for (int k = 0; k < 6; ++k) {
        const int f = tid + 256 * k, j = f >> 5, c4 = (f & 31) * 4;
        const float* src = (j < C0_N)
            ? &w0[((size_t)c * C0_N + j) * D_N + d0 + c4]
            : &w1[((size_t)c * C1_N + (j - C0_N)) * D_N + d0 + c4];
        const float4 v = *(const float4*)src;
        unsigned short* dst = &ws[c4 >> 3][j][c4 & 4];
        dst[0] = (unsigned short)f2bf(v.x); dst[1] = (unsigned short)f2bf(v.y);
        dst[2] = (unsigned short)f2bf(v.z); dst[3] = (unsigned short)f2bf(v.w);
    }
    __syncthreads();   // rl visible before gather
    // stage gathered x rows: 64 rows x 128 floats
    #pragma unroll
    for (int k = 0; k < 8; ++k) {
        const int f = tid + 256 * k, r = f >> 5, c4 = (f & 31) * 4;
        const float4 v = *(const float4*)&x[(size_t)rl[r] * D_N + d0 + c4];
        unsigned short* dst = &xs[c4 >> 3][r][c4 & 4];
        dst[0] = (unsigned short)f2bf(v.x); dst[1] = (unsigned short)f2bf(v.y);
        dst[2] = (unsigned short)f2bf(v.z); dst[3] = (unsigned short)f2bf(v.w);
    }
    __syncthreads();

    const int lane = tid & 63;
    const int wv   = tid >> 6;
    const int lr   = lane & 15;
    const int lg   = lane >> 4;

    f32x4 acc0 = {0.f, 0.f, 0.f, 0.f};
    f32x4 acc1 = {0.f, 0.f, 0.f, 0.f};
    f32x4 acc2 = {0.f, 0.f, 0.f, 0.f};
    #pragma unroll
    for (int ks = 0; ks < 4; ++ks) {
        const int kq = ks * 4 + lg;
        const short8v a  = *(const short8v*)&xs[kq][wv * 16 + lr][0];
        const short8v bA = *(const short8v*)&ws[kq][lr][0];
        const short8v bB = *(const short8v*)&ws[kq][16 + lr][0];
        const short8v bC = *(const short8v*)&ws[kq][32 + lr][0];
        acc0 = __builtin_amdgcn_mfma_f32_16x16x32_bf16(a, bA, acc0, 0, 0, 0);
        acc1 = __builtin_amdgcn_mfma_f32_16x16x32_bf16(a, bB, acc1, 0, 0, 0);
        acc2 = __builtin_amdgcn_mfma_f32_16x16x32_bf16(a, bC, acc2, 0, 0, 0);
    }

    #pragma unroll
    for (int reg = 0; reg < 4; ++reg) {
        const int rr = wv * 16 + lg * 4 + reg;
        if (rr < m) {
            const int row = rl[rr];
            #pragma unroll
            for (int nt = 0; nt < 3; ++nt) {
                const int jj = nt * 16 + lr;
                float v = (nt == 0) ? acc0[reg] : (nt == 1) ? acc1[reg] : acc2[reg];
                if (kc == 0)
                    v += (jj < C0_N) ? b0[c * C0_N + jj]
                                     : b1[c * C1_N + (jj - C0_N)];
                if (jj < C0_N)
                    atomicAdd(&out_c0[(size_t)row * C0_N + jj], v);
                else
                    atomicAdd(&out_c1[(size_t)row * C1_N + (jj - C0_N)], v);
            }
        }
    }
}

// ---------------------------------------------------------------------------
extern "C" void kernel_launch(void* const* d_in, const int* in_sizes, int n_in,
                              void* d_out, int out_size, void* d_ws, size_t ws_size,
                              hipStream_t stream) {
    const float* x  = (const float*)d_in[0];
    const float* pw = (const float*)d_in[1];
    const float* pb = (const float*)d_in[2];
    const float* w0 = (const float*)d_in[3];
    const float* b0 = (const float*)d_in[4];
    const float* w1 = (const float*)d_in[5];
    const float* b1 = (const float*)d_in[6];

    float* out_logits = (float*)d_out;                       // [4096][64]
    float* out_c0     = out_logits + (size_t)B_N * P_N;      // [4096][16]
    float* out_c1     = out_c0     + (size_t)B_N * C0_N;     // [4096][32]

    // ws: [counts 64] [lists 64*4096]
    int* counts = (int*)d_ws;
    int* lists  = counts + 64;

    hipMemsetAsync(counts, 0, P_N * sizeof(int), stream);

    hc_parent_fused<<<B_N / PR, 512, 0, stream>>>(
        x, pw, pb, out_logits, out_c0, counts, lists);

    hc_child_mfma<<<dim3(P_N, KC2, 3), 256, 0, stream>>>(
        x, w0, w1, b0, b1, counts, lists, out_c0, out_c1);
}

// Round 24
// 59.597 us; speedup vs baseline: 1.1957x; 1.0329x over previous
//
#include <hip/hip_runtime.h>
#include <hip/hip_bf16.h>

// Sizes fixed by the reference problem.
#define B_N   4096
#define D_N   1024
#define P_N   64
#define C0_N  16
#define C1_N  32
#define NC_N  48    // C0 + C1 concatenated

// parent GEMM K-split (r24: KC1 8, 32-row x K=128 blocks; partials 8.4MB)
#define KC1   8
#define DKC1  128
#define AR    32     // rows per A block

// child GEMM K-split — KC2 MUST stay 8 (r14/r16: 16 writers/row -> ~30x HBM amp).
#define KC2   8
#define DKC2  128
#define TRC   64     // child MFMA row tile

// Tie physics: fp32 softmax probs can only tie when the true logit gap is
// <~2e-7. With the 3-pass bf16-split parent GEMM the logit error is ~2-3e-8,
// so tau=1e-6 keeps ~25x margin; ~15-30 suspect rows total.
#define GAP_TAU 1e-6f
#define NEG_INF (-3.402823466e38f)

// Lessons (r10-r23): no grid.sync; no per-block device fences; >=3 blocks/CU
// AND >=500 blocks (r22/r23: fused 1-block/CU full-K parent = 52-62us,
// latency-doomed regardless of waves); LDS kq-plane strides != 0 mod 128B;
// child KC2=8 only; single-writer 256B chunks; 3-dispatch chain minimum.

typedef __attribute__((ext_vector_type(8))) short short8v;
typedef __attribute__((ext_vector_type(4))) float f32x4;

static __device__ __forceinline__ unsigned f2bf(float f) {
    union { float f; unsigned u; } v; v.f = f;
    return (v.u + 0x7FFF + ((v.u >> 16) & 1)) >> 16;   // RNE, low 16 valid
}
// split float4 into packed-hi (2x uint) and packed-lo residual (2x uint)
static __device__ __forceinline__ void split4(float4 v, uint2& hp, uint2& lp) {
    const unsigned hx = f2bf(v.x), hy = f2bf(v.y);
    const unsigned hz = f2bf(v.z), hw = f2bf(v.w);
    union { unsigned u; float f; } t;
    float rx, ry, rz, rw;
    t.u = hx << 16; rx = v.x - t.f;
    t.u = hy << 16; ry = v.y - t.f;
    t.u = hz << 16; rz = v.z - t.f;
    t.u = hw << 16; rw = v.w - t.f;
    hp.x = hx | (hy << 16);             hp.y = hz | (hw << 16);
    lp.x = f2bf(rx) | (f2bf(ry) << 16); lp.y = f2bf(rz) | (f2bf(rw) << 16);
}

// ===========================================================================
// A: parent-logit partials via error-compensated bf16 MFMA.
// r24 geometry: block = 32 rows x 64 parents x K=128; grid (128 tiles, 8 kc)
// = 1024 blocks, 3/CU (LDS 50.2KB). Padded k-major LDS (r23-proven):
// xh/xl [16][33][8] (+4 banks/plane), wh/wl [16][65][8] (+4 banks/plane).
// Wave wv: row-half rh=wv&1, parent-half ph=wv>>1 (2 n-tiles); 3-pass split
// MFMA (xh*wh + xl*wh + xh*wl), fp32 acc. Partials [row][kc8][64]: 256B
// single-writer chunks (the child's proven-quiet pattern).
// Block (0,0) zeroes counts.
// ===========================================================================
__global__ __launch_bounds__(256, 3)
void hc_parent_mfma(const float* __restrict__ x,
                    const float* __restrict__ pw,
                    float* __restrict__ partials,
                    int* __restrict__ counts) {
    __shared__ unsigned short xh[16][33][8], xl[16][33][8];
    __shared__ unsigned short wh[16][65][8], wl[16][65][8];

    const int tid = threadIdx.x;
    if (blockIdx.x == 0 && blockIdx.y == 0 && tid < P_N) counts[tid] = 0;

    const int r0 = blockIdx.x * AR;
    const int d0 = blockIdx.y * DKC1;

    // stage + split x: 32 rows x 128 floats = 1024 float4, 4 per thread
    #pragma unroll
    for (int k = 0; k < 4; ++k) {
        const int f = tid + 256 * k, r = f >> 5, c4 = (f & 31) * 4;
        const float4 v = *(const float4*)&x[(size_t)(r0 + r) * D_N + d0 + c4];
        uint2 hp, lp; split4(v, hp, lp);
        *(uint2*)&xh[c4 >> 3][r][c4 & 4] = hp;
        *(uint2*)&xl[c4 >> 3][r][c4 & 4] = lp;
    }
    // stage + split pw chunk: 64 parents x 128 floats = 2048 float4, 8/thread
    #pragma unroll
    for (int k = 0; k < 8; ++k) {
        const int f = tid + 256 * k, r = f >> 5, c4 = (f & 31) * 4;
        const float4 v = *(const float4*)&pw[(size_t)r * D_N + d0 + c4];
        uint2 hp, lp; split4(v, hp, lp);
        *(uint2*)&wh[c4 >> 3][r][c4 & 4] = hp;
        *(uint2*)&wl[c4 >> 3][r][c4 & 4] = lp;
    }
    __syncthreads();

    const int lane = tid & 63;
    const int wv   = tid >> 6;     // 0..3
    const int lr   = lane & 15;
    const int lg   = lane >> 4;
    const int rh   = wv & 1;       // row half: rows rh*16 .. rh*16+15
    const int ph   = wv >> 1;      // parent half: parents ph*32 .. ph*32+31

    f32x4 acc[2] = {{0.f,0.f,0.f,0.f}, {0.f,0.f,0.f,0.f}};
    #pragma unroll
    for (int ks = 0; ks < 4; ++ks) {
        const int kq = ks * 4 + lg;
        const short8v ah = *(const short8v*)&xh[kq][rh * 16 + lr][0];
        const short8v al = *(const short8v*)&xl[kq][rh * 16 + lr][0];
        #pragma unroll
        for (int nt = 0; nt < 2; ++nt) {
            const short8v bh = *(const short8v*)&wh[kq][ph * 32 + nt * 16 + lr][0];
            const short8v bl = *(const short8v*)&wl[kq][ph * 32 + nt * 16 + lr][0];
            acc[nt] = __builtin_amdgcn_mfma_f32_16x16x32_bf16(ah, bh, acc[nt], 0, 0, 0);
            acc[nt] = __builtin_amdgcn_mfma_f32_16x16x32_bf16(al, bh, acc[nt], 0, 0, 0);
            acc[nt] = __builtin_amdgcn_mfma_f32_16x16x32_bf16(ah, bl, acc[nt], 0, 0, 0);
        }
    }

    // epilogue: D x-row = rh*16 + lg*4 + reg, parent = ph*32 + nt*16 + lr
    const int kcb = blockIdx.y;
    #pragma unroll
    for (int reg = 0; reg < 4; ++reg) {
        const int rr = rh * 16 + lg * 4 + reg;
        const size_t rbase =
            (size_t)(r0 + rr) * (KC1 * P_N) + (size_t)kcb * P_N;
        #pragma unroll
        for (int nt = 0; nt < 2; ++nt)
            partials[rbase + ph * 32 + nt * 16 + lr] = acc[nt][reg];
    }
}

// ===========================================================================
// B: route + block-local cooperative f64 fixup + output zeroing (proven
// r19/r21; KC1=8 reduce). Block = 4 rows; zeroes its 768B c0/c1 slice.
// Near-ties -> LDS queue -> block-cooperative f64 softmax-emulation fixup
// (first-index argmax on fp32-quantized probs).
// ===========================================================================
__global__ __launch_bounds__(256, 6)
void hc_parent_route(const float* __restrict__ partials,
                     const float* __restrict__ pb,
                     const float* __restrict__ x,
                     const float* __restrict__ pw,
                     float* __restrict__ out_logits,
                     float* __restrict__ out_cz,      // = out_c0 (contig c0|c1)
                     int* __restrict__ counts,
                     int* __restrict__ lists) {
    __shared__ double ld[P_N];
    __shared__ int    sq[8];
    __shared__ int    sqn;

    const int tid = threadIdx.x;
    const int p   = tid & 63;
    const int w   = tid >> 6;
    const int row = blockIdx.x * 4 + w;

    if (tid == 0) sqn = 0;

    // ---- zero this block's slice of the child outputs (192 floats) ----
    if (tid < 48)
        ((float4*)(out_cz + (size_t)blockIdx.x * 192))[tid] =
            make_float4(0.f, 0.f, 0.f, 0.f);

    // ---- fast path ----
    const float* prow = &partials[(size_t)row * (KC1 * P_N)];
    float lv[KC1];
    #pragma unroll
    for (int kc = 0; kc < KC1; ++kc) lv[kc] = prow[kc * P_N + p];
    float l = pb[p];
    #pragma unroll
    for (int kc = 0; kc < KC1; ++kc) l += lv[kc];

    out_logits[(size_t)row * P_N + p] = l;

    float m1 = l; int i1 = p; float m2 = NEG_INF;
    #pragma unroll
    for (int off = 32; off > 0; off >>= 1) {
        const float om1 = __shfl_xor(m1, off);
        const int   oi1 = __shfl_xor(i1, off);
        const float om2 = __shfl_xor(m2, off);
        if (om1 > m1 || (om1 == m1 && oi1 < i1)) {
            m2 = fmaxf(m1, om2); m1 = om1; i1 = oi1;
        } else m2 = fmaxf(m2, om1);
    }
    if (p == 0) {
        if (m1 - m2 > GAP_TAU) {
            const int pos = atomicAdd(&counts[i1], 1);
            lists[i1 * B_N + pos] = row;
        } else {
            const int q = atomicAdd(&sqn, 1);
            sq[q] = row;
        }
    }
    __syncthreads();

    const int nq = sqn;
    if (nq == 0) return;    // uniform: all threads past the barrier

    for (int qi = 0; qi < nq; ++qi) {
        const int srow = sq[qi];
        const float* xr = &x[(size_t)srow * D_N + p * 16];
        float4 xv[4];
        #pragma unroll
        for (int k = 0; k < 4; ++k) xv[k] = *(const float4*)&xr[k * 4];

        #pragma unroll 2
        for (int pass = 0; pass < 16; ++pass) {
            const int pp = w * 16 + pass;
            const float* wr = &pw[(size_t)pp * D_N + p * 16];
            double a0 = 0.0, a1 = 0.0, a2 = 0.0, a3 = 0.0;
            #pragma unroll
            for (int k = 0; k < 4; ++k) {
                const float4 wv2 = *(const float4*)&wr[k * 4];
                a0 = fma((double)wv2.x, (double)xv[k].x, a0);
                a1 = fma((double)wv2.y, (double)xv[k].y, a1);
                a2 = fma((double)wv2.z, (double)xv[k].z, a2);
                a3 = fma((double)wv2.w, (double)xv[k].w, a3);
            }
            double a = (a0 + a1) + (a2 + a3);
            #pragma unroll
            for (int off = 32; off > 0; off >>= 1) a += __shfl_xor(a, off);
            if (p == 0) ld[pp] = a;
        }
        __syncthreads();

        if (w == 0) {
            const double accv = (double)pb[p] + ld[p];
            const float  l32  = (float)accv;
            float m = l32;
            #pragma unroll
            for (int off = 32; off > 0; off >>= 1)
                m = fmaxf(m, __shfl_xor(m, off));
            const float e = (float)exp((double)(l32 - m));  // correctly-rounded
            double es = (double)e;
            #pragma unroll
            for (int off = 32; off > 0; off >>= 1) es += __shfl_xor(es, off);
            es = __shfl(es, 0);
            const float s    = (float)es;
            const float prob = e / s;    // IEEE f32 divide: ties survive
            float pm = prob; int pi = p;
            #pragma unroll
            for (int off = 32; off > 0; off >>= 1) {
                const float opm = __shfl_xor(pm, off);
                const int   opi = __shfl_xor(pi, off);
                if (opm > pm || (opm == pm && opi < pi)) { pm = opm; pi = opi; }
            }
            if (p == 0) {
                const int pos = atomicAdd(&counts[pi], 1);
                lists[pi * B_N + pos] = srow;
            }
        }
        __syncthreads();
    }
}

// ===========================================================================
// C: child GEMM via bf16 MFMA (proven r20/21). Tile 64 rows x 48 outs x
// K=128. LDS k-major [16][row][8] bf16, lane-contiguous fragments.
// atomicAdd epilogue onto B-zeroed outputs, bias at kc==0. UNCHANGED.
// ===========================================================================
__global__ __launch_bounds__(256, 5)
void hc_child_mfma(const float* __restrict__ x,
                   const float* __restrict__ w0,
                   const float* __restrict__ w1,
                   const float* __restrict__ b0,
                   const float* __restrict__ b1,
                   const int* __restrict__ counts,
                   const int* __restrict__ lists,
                   float* __restrict__ out_c0,
                   float* __restrict__ out_c1) {
    const int c  = blockIdx.x;
    const int kc = blockIdx.y;
    const int n  = counts[c];
    const int t0 = blockIdx.z * TRC;
    if (t0 >= n) return;
    const int m  = min(TRC, n - t0);
    const int d0 = kc * DKC2;

    __shared__ int            rl[TRC];
    __shared__ unsigned short xs[16][TRC][8];    // [kchunk][row][8k] bf16
    __shared__ unsigned short ws[16][NC_N][8];   // [kchunk][out][8k] bf16

    const int tid = threadIdx.x;
    if (tid < TRC)
        rl[tid] = lists[c * B_N + t0 + (tid < m ? tid : 0)];

    // stage weights: 48 rows x 128 floats
    #pragma unroll
    for (int k = 0; k < 6; ++k) {
        const int f = tid + 256 * k, j = f >> 5, c4 = (f & 31) * 4;
        const float* src = (j < C0_N)
            ? &w0[((size_t)c * C0_N + j) * D_N + d0 + c4]
            : &w1[((size_t)c * C1_N + (j - C0_N)) * D_N + d0 + c4];
        const float4 v = *(const float4*)src;
        unsigned short* dst = &ws[c4 >> 3][j][c4 & 4];
        dst[0] = (unsigned short)f2bf(v.x); dst[1] = (unsigned short)f2bf(v.y);
        dst[2] = (unsigned short)f2bf(v.z); dst[3] = (unsigned short)f2bf(v.w);
    }
    __syncthreads();   // rl visible before gather
    // stage gathered x rows: 64 rows x 128 floats
    #pragma unroll
    for (int k = 0; k < 8; ++k) {
        const int f = tid + 256 * k, r = f >> 5, c4 = (f & 31) * 4;
        const float4 v = *(const float4*)&x[(size_t)rl[r] * D_N + d0 + c4];
        unsigned short* dst = &xs[c4 >> 3][r][c4 & 4];
        dst[0] = (unsigned short)f2bf(v.x); dst[1] = (unsigned short)f2bf(v.y);
        dst[2] = (unsigned short)f2bf(v.z); dst[3] = (unsigned short)f2bf(v.w);
    }
    __syncthreads();

    const int lane = tid & 63;
    const int wv   = tid >> 6;
    const int lr   = lane & 15;
    const int lg   = lane >> 4;

    f32x4 acc0 = {0.f, 0.f, 0.f, 0.f};
    f32x4 acc1 = {0.f, 0.f, 0.f, 0.f};
    f32x4 acc2 = {0.f, 0.f, 0.f, 0.f};
    #pragma unroll
    for (int ks = 0; ks < 4; ++ks) {
        const int kq = ks * 4 + lg;
        const short8v a  = *(const short8v*)&xs[kq][wv * 16 + lr][0];
        const short8v bA = *(const short8v*)&ws[kq][lr][0];
        const short8v bB = *(const short8v*)&ws[kq][16 + lr][0];
        const short8v bC = *(const short8v*)&ws[kq][32 + lr][0];
        acc0 = __builtin_amdgcn_mfma_f32_16x16x32_bf16(a, bA, acc0, 0, 0, 0);
        acc1 = __builtin_amdgcn_mfma_f32_16x16x32_bf16(a, bB, acc1, 0, 0, 0);
        acc2 = __builtin_amdgcn_mfma_f32_16x16x32_bf16(a, bC, acc2, 0, 0, 0);
    }

    #pragma unroll
    for (int reg = 0; reg < 4; ++reg) {
        const int rr = wv * 16 + lg * 4 + reg;
        if (rr < m) {
            const int row = rl[rr];
            #pragma unroll
            for (int nt = 0; nt < 3; ++nt) {
                const int jj = nt * 16 + lr;
                float v = (nt == 0) ? acc0[reg] : (nt == 1) ? acc1[reg] : acc2[reg];
                if (kc == 0)
                    v += (jj < C0_N) ? b0[c * C0_N + jj]
                                     : b1[c * C1_N + (jj - C0_N)];
                if (jj < C0_N)
                    atomicAdd(&out_c0[(size_t)row * C0_N + jj], v);
                else
                    atomicAdd(&out_c1[(size_t)row * C1_N + (jj - C0_N)], v);
            }
        }
    }
}

// ---------------------------------------------------------------------------
extern "C" void kernel_launch(void* const* d_in, const int* in_sizes, int n_in,
                              void* d_out, int out_size, void* d_ws, size_t ws_size,
                              hipStream_t stream) {
    const float* x  = (const float*)d_in[0];
    const float* pw = (const float*)d_in[1];
    const float* pb = (const float*)d_in[2];
    const float* w0 = (const float*)d_in[3];
    const float* b0 = (const float*)d_in[4];
    const float* w1 = (const float*)d_in[5];
    const float* b1 = (const float*)d_in[6];

    float* out_logits = (float*)d_out;                       // [4096][64]
    float* out_c0     = out_logits + (size_t)B_N * P_N;      // [4096][16]
    float* out_c1     = out_c0     + (size_t)B_N * C0_N;     // [4096][32]

    // ws: [counts 64] [lists 64*4096] [partials 8.4MB]
    int*   counts   = (int*)d_ws;
    int*   lists    = counts + 64;
    float* partials = (float*)(lists + P_N * B_N);

    hc_parent_mfma<<<dim3(B_N / AR, KC1), 256, 0, stream>>>(
        x, pw, partials, counts);

    hc_parent_route<<<B_N / 4, 256, 0, stream>>>(
        partials, pb, x, pw, out_logits, out_c0, counts, lists);

    hc_child_mfma<<<dim3(P_N, KC2, 3), 256, 0, stream>>>(
        x, w0, w1, b0, b1, counts, lists, out_c0, out_c1);
}

// Round 25
// 44.521 us; speedup vs baseline: 1.6006x; 1.3386x over previous
//
#include <hip/hip_runtime.h>
#include <hip/hip_bf16.h>

// Sizes fixed by the reference problem.
#define B_N   4096
#define D_N   1024
#define P_N   64
#define C0_N  16
#define C1_N  32
#define NC_N  48    // C0 + C1 concatenated

// fused parent geometry (r25): 512 blocks x 8 rows x FULL K; 3 blocks/CU
#define PRR   8      // rows per P block
#define PKC   8      // serial K chunks
#define PDK   128    // chunk depth

// child GEMM K-split — KC2 MUST stay 8 (r14/r16: 16 writers/row -> ~30x HBM amp).
#define KC2   8
#define DKC2  128
#define TRC   64     // child MFMA row tile

// Tie physics: fp32 softmax probs can only tie when the true logit gap is
// <~2e-7. With the 3-pass bf16-split parent GEMM the logit error is ~2-3e-8,
// so tau=1e-6 keeps ~25x margin; ~15-30 suspect rows total.
#define GAP_TAU 1e-6f
#define NEG_INF (-3.402823466e38f)

// Lessons (r10-r24): no grid.sync; no per-block device fences; full-K-per-
// block needs >=3 co-resident blocks/CU (r22/r23: 1/CU = 52-62us); >=500
// blocks; LDS kq-plane strides != 0 mod 128B; child KC2=8 only; minimize
// dispatches. r25: 2-dispatch chain — P routes via pclass (NO atomics, no
// counts/lists); C rebuilds per-class lists via r12's proven prefix-scan.

typedef __attribute__((ext_vector_type(8))) short short8v;
typedef __attribute__((ext_vector_type(4))) float f32x4;

static __device__ __forceinline__ unsigned f2bf(float f) {
    union { float f; unsigned u; } v; v.f = f;
    return (v.u + 0x7FFF + ((v.u >> 16) & 1)) >> 16;   // RNE, low 16 valid
}
// split float4 into packed-hi (2x uint) and packed-lo residual (2x uint)
static __device__ __forceinline__ void split4(float4 v, uint2& hp, uint2& lp) {
    const unsigned hx = f2bf(v.x), hy = f2bf(v.y);
    const unsigned hz = f2bf(v.z), hw = f2bf(v.w);
    union { unsigned u; float f; } t;
    float rx, ry, rz, rw;
    t.u = hx << 16; rx = v.x - t.f;
    t.u = hy << 16; ry = v.y - t.f;
    t.u = hz << 16; rz = v.z - t.f;
    t.u = hw << 16; rw = v.w - t.f;
    hp.x = hx | (hy << 16);             hp.y = hz | (hw << 16);
    lp.x = f2bf(rx) | (f2bf(ry) << 16); lp.y = f2bf(rz) | (f2bf(rw) << 16);
}

// ===========================================================================
// P: fused parent — full-K bf16-split MFMA logits + route + fixup + zeroing.
// 512 blocks x 256 threads (4 waves), 3 blocks/CU (LDS ~43KB) so serial
// chunk chains of co-resident blocks overlap. Block = 8 rows x 64 parents.
// Per K=128 chunk: stage+split x (8x128; fragment rows 8-15 are discarded
// padding) and pw (64x128) into padded k-major LDS; wave wv owns parent
// tile wv: 3-pass MFMA (xh*wh + xl*wh + xh*wl), fp32 acc across chunks.
// Route: logits->LDS(+pb), wave wv routes rows wv*2..wv*2+1 (top-2, tau),
// writing pclass[row] — NO atomics. Near-ties -> LDS queue -> block-
// cooperative f64 softmax emulation (first-index argmax on fp32-quantized
// probs) -> pclass. Also zeroes this block's 384-float c0/c1 slice.
// ===========================================================================
__global__ __launch_bounds__(256, 3)
void hc_parent_fused(const float* __restrict__ x,
                     const float* __restrict__ pw,
                     const float* __restrict__ pb,
                     float* __restrict__ out_logits,
                     float* __restrict__ out_cz,      // = out_c0 (contig c0|c1)
                     int* __restrict__ pclass) {
    __shared__ unsigned short xh[16][17][8], xl[16][17][8];   // rows 8-15 pad
    __shared__ unsigned short wh[16][65][8], wl[16][65][8];
    __shared__ float  llds[PRR][68];
    __shared__ double ld[P_N];
    __shared__ int    sq[PRR];
    __shared__ int    sqn;

    const int tid = threadIdx.x;
    const int r0  = blockIdx.x * PRR;

    if (tid == 0) sqn = 0;
    // zero this block's c0/c1 slice: 8 rows x 48 = 384 floats = 96 float4
    if (tid < 96)
        ((float4*)(out_cz + (size_t)blockIdx.x * (PRR * NC_N)))[tid] =
            make_float4(0.f, 0.f, 0.f, 0.f);

    const int lane = tid & 63;
    const int wv   = tid >> 6;     // 0..3 = parent tile
    const int lr   = lane & 15;
    const int lg   = lane >> 4;

    f32x4 acc = {0.f, 0.f, 0.f, 0.f};

    for (int kc = 0; kc < PKC; ++kc) {
        const int d0 = kc * PDK;
        __syncthreads();               // protect previous chunk's LDS reads
        // stage + split x: 8 rows x 128 floats = 256 float4, 1 per thread
        {
            const int r = tid >> 5, c4 = (tid & 31) * 4;
            const float4 v = *(const float4*)&x[(size_t)(r0 + r) * D_N + d0 + c4];
            uint2 hp, lp; split4(v, hp, lp);
            *(uint2*)&xh[c4 >> 3][r][c4 & 4] = hp;
            *(uint2*)&xl[c4 >> 3][r][c4 & 4] = lp;
        }
        // stage + split pw chunk: 64 parents x 128 floats = 2048 f4, 8/thread
        #pragma unroll
        for (int k = 0; k < 8; ++k) {
            const int f = tid + 256 * k, r = f >> 5, c4 = (f & 31) * 4;
            const float4 v = *(const float4*)&pw[(size_t)r * D_N + d0 + c4];
            uint2 hp, lp; split4(v, hp, lp);
            *(uint2*)&wh[c4 >> 3][r][c4 & 4] = hp;
            *(uint2*)&wl[c4 >> 3][r][c4 & 4] = lp;
        }
        __syncthreads();

        #pragma unroll
        for (int ks = 0; ks < 4; ++ks) {
            const int kq = ks * 4 + lg;
            const short8v ah = *(const short8v*)&xh[kq][lr][0];
            const short8v al = *(const short8v*)&xl[kq][lr][0];
            const short8v bh = *(const short8v*)&wh[kq][wv * 16 + lr][0];
            const short8v bl = *(const short8v*)&wl[kq][wv * 16 + lr][0];
            acc = __builtin_amdgcn_mfma_f32_16x16x32_bf16(ah, bh, acc, 0, 0, 0);
            acc = __builtin_amdgcn_mfma_f32_16x16x32_bf16(al, bh, acc, 0, 0, 0);
            acc = __builtin_amdgcn_mfma_f32_16x16x32_bf16(ah, bl, acc, 0, 0, 0);
        }
    }
    __syncthreads();
    // D layout (m89-validated): x-row = lg*4+reg, parent = wv*16+lr.
    // Only lg<2 lanes hold real rows (0..7); others are padding.
    if (lg < 2) {
        #pragma unroll
        for (int reg = 0; reg < 4; ++reg)
            llds[lg * 4 + reg][wv * 16 + lr] = acc[reg];
    }
    __syncthreads();

    // ---- route: wave wv handles rows wv*2, wv*2+1 ----
    const int p = lane;
    #pragma unroll
    for (int rq = 0; rq < 2; ++rq) {
        const int rloc = wv * 2 + rq;
        const int row  = r0 + rloc;
        const float l  = llds[rloc][p] + pb[p];
        out_logits[(size_t)row * P_N + p] = l;

        float m1 = l; int i1 = p; float m2 = NEG_INF;
        #pragma unroll
        for (int off = 32; off > 0; off >>= 1) {
            const float om1 = __shfl_xor(m1, off);
            const int   oi1 = __shfl_xor(i1, off);
            const float om2 = __shfl_xor(m2, off);
            if (om1 > m1 || (om1 == m1 && oi1 < i1)) {
                m2 = fmaxf(m1, om2); m1 = om1; i1 = oi1;
            } else m2 = fmaxf(m2, om1);
        }
        if (p == 0) {
            if (m1 - m2 > GAP_TAU) {
                pclass[row] = i1;                 // no atomics
            } else {
                const int q = atomicAdd(&sqn, 1); // LDS only
                sq[q] = row;
            }
        }
    }
    __syncthreads();

    const int nq = sqn;
    if (nq == 0) return;    // uniform across the block

    // ---- block-cooperative f64 fixup (~26 suspect rows chip-wide) ----
    for (int qi = 0; qi < nq; ++qi) {
        const int srow = sq[qi];
        const float* xr = &x[(size_t)srow * D_N + p * 16];
        float4 xv[4];
        #pragma unroll
        for (int k = 0; k < 4; ++k) xv[k] = *(const float4*)&xr[k * 4];

        #pragma unroll 2
        for (int pass = 0; pass < 16; ++pass) {
            const int pp = wv * 16 + pass;
            const float* wr = &pw[(size_t)pp * D_N + p * 16];
            double a0 = 0.0, a1 = 0.0, a2 = 0.0, a3 = 0.0;
            #pragma unroll
            for (int k = 0; k < 4; ++k) {
                const float4 wv2 = *(const float4*)&wr[k * 4];
                a0 = fma((double)wv2.x, (double)xv[k].x, a0);
                a1 = fma((double)wv2.y, (double)xv[k].y, a1);
                a2 = fma((double)wv2.z, (double)xv[k].z, a2);
                a3 = fma((double)wv2.w, (double)xv[k].w, a3);
            }
            double a = (a0 + a1) + (a2 + a3);
            #pragma unroll
            for (int off = 32; off > 0; off >>= 1) a += __shfl_xor(a, off);
            if (p == 0) ld[pp] = a;
        }
        __syncthreads();

        if (wv == 0) {
            const double accv = (double)pb[p] + ld[p];
            const float  l32  = (float)accv;
            float m = l32;
            #pragma unroll
            for (int off = 32; off > 0; off >>= 1)
                m = fmaxf(m, __shfl_xor(m, off));
            const float e = (float)exp((double)(l32 - m));  // correctly-rounded
            double es = (double)e;
            #pragma unroll
            for (int off = 32; off > 0; off >>= 1) es += __shfl_xor(es, off);
            es = __shfl(es, 0);
            const float s    = (float)es;
            const float prob = e / s;    // IEEE f32 divide: ties survive
            float pm = prob; int pi = p;
            #pragma unroll
            for (int off = 32; off > 0; off >>= 1) {
                const float opm = __shfl_xor(pm, off);
                const int   opi = __shfl_xor(pi, off);
                if (opm > pm || (opm == pm && opi < pi)) { pm = opm; pi = opi; }
            }
            if (p == 0) pclass[srow] = pi;
        }
        __syncthreads();
    }
}

// ===========================================================================
// C: child GEMM via bf16 MFMA + per-block pclass scan (r12's proven
// compaction; deterministic row-ascending list, no counts/lists buffers).
// Grid (64 classes, 8 kc, 3 slots of 64 rows); every block scans pclass
// (16KB coalesced) + 8-step Hillis-Steele, then ghost slots exit.
// MFMA tile 64 rows x 48 outs x K=128; atomicAdd epilogue onto P-zeroed
// outputs, bias folded at kc==0. LDS ~30KB -> 5 blocks/CU.
// ===========================================================================
__global__ __launch_bounds__(256, 5)
void hc_child_mfma(const float* __restrict__ x,
                   const float* __restrict__ w0,
                   const float* __restrict__ w1,
                   const float* __restrict__ b0,
                   const float* __restrict__ b1,
                   const int* __restrict__ pclass,
                   float* __restrict__ out_c0,
                   float* __restrict__ out_c1) {
    const int c  = blockIdx.x;
    const int kc = blockIdx.y;
    const int t0 = blockIdx.z * TRC;
    const int d0 = kc * DKC2;

    __shared__ int            scnt[256];
    __shared__ int            slist[TRC];
    __shared__ unsigned short xs[16][TRC][8];    // [kchunk][row][8k] bf16
    __shared__ unsigned short ws[16][NC_N][8];   // [kchunk][out][8k] bf16

    const int tid = threadIdx.x;

    // ---- scan pclass: count + prefix-sum + compact this slot's window ----
    const int rbase = tid * 16;
    int myc = 0;
    #pragma unroll
    for (int k = 0; k < 16; ++k)
        myc += (pclass[rbase + k] == c) ? 1 : 0;
    scnt[tid] = myc;
    __syncthreads();
    for (int off = 1; off < 256; off <<= 1) {     // inclusive Hillis-Steele
        const int v = scnt[tid];
        const int u = (tid >= off) ? scnt[tid - off] : 0;
        __syncthreads();
        scnt[tid] = v + u;
        __syncthreads();
    }
    const int excl = scnt[tid] - myc;
    const int n    = scnt[255];
    if (t0 >= n) return;                          // uniform ghost-slot exit
    const int m = min(TRC, n - t0);
    {
        int pos = excl;
        #pragma unroll
        for (int k = 0; k < 16; ++k) {
            const int row = rbase + k;
            if (pclass[row] == c) {
                const int rel = pos - t0;
                if (rel >= 0 && rel < TRC) slist[rel] = row;
                ++pos;
            }
        }
    }
    __syncthreads();                              // slist complete

    // ---- stage weights: 48 rows x 128 floats ----
    #pragma unroll
    for (int k = 0; k < 6; ++k) {
        const int f = tid + 256 * k, j = f >> 5, c4 = (f & 31) * 4;
        const float* src = (j < C0_N)
            ? &w0[((size_t)c * C0_N + j) * D_N + d0 + c4]
            : &w1[((size_t)c * C1_N + (j - C0_N)) * D_N + d0 + c4];
        const float4 v = *(const float4*)src;
        unsigned short* dst = &ws[c4 >> 3][j][c4 & 4];
        dst[0] = (unsigned short)f2bf(v.x); dst[1] = (unsigned short)f2bf(v.y);
        dst[2] = (unsigned short)f2bf(v.z); dst[3] = (unsigned short)f2bf(v.w);
    }
    // ---- stage gathered x rows: 64 rows x 128 floats ----
    #pragma unroll
    for (int k = 0; k < 8; ++k) {
        const int f = tid + 256 * k, r = f >> 5, c4 = (f & 31) * 4;
        const int row = slist[r < m ? r : 0];
        const float4 v = *(const float4*)&x[(size_t)row * D_N + d0 + c4];
        unsigned short* dst = &xs[c4 >> 3][r][c4 & 4];
        dst[0] = (unsigned short)f2bf(v.x); dst[1] = (unsigned short)f2bf(v.y);
        dst[2] = (unsigned short)f2bf(v.z); dst[3] = (unsigned short)f2bf(v.w);
    }
    __syncthreads();

    const int lane = tid & 63;
    const int wv   = tid >> 6;
    const int lr   = lane & 15;
    const int lg   = lane >> 4;

    f32x4 acc0 = {0.f, 0.f, 0.f, 0.f};
    f32x4 acc1 = {0.f, 0.f, 0.f, 0.f};
    f32x4 acc2 = {0.f, 0.f, 0.f, 0.f};
    #pragma unroll
    for (int ks = 0; ks < 4; ++ks) {
        const int kq = ks * 4 + lg;
        const short8v a  = *(const short8v*)&xs[kq][wv * 16 + lr][0];
        const short8v bA = *(const short8v*)&ws[kq][lr][0];
        const short8v bB = *(const short8v*)&ws[kq][16 + lr][0];
        const short8v bC = *(const short8v*)&ws[kq][32 + lr][0];
        acc0 = __builtin_amdgcn_mfma_f32_16x16x32_bf16(a, bA, acc0, 0, 0, 0);
        acc1 = __builtin_amdgcn_mfma_f32_16x16x32_bf16(a, bB, acc1, 0, 0, 0);
        acc2 = __builtin_amdgcn_mfma_f32_16x16x32_bf16(a, bC, acc2, 0, 0, 0);
    }

    #pragma unroll
    for (int reg = 0; reg < 4; ++reg) {
        const int rr = wv * 16 + lg * 4 + reg;
        if (rr < m) {
            const int row = slist[rr];
            #pragma unroll
            for (int nt = 0; nt < 3; ++nt) {
                const int jj = nt * 16 + lr;
                float v = (nt == 0) ? acc0[reg] : (nt == 1) ? acc1[reg] : acc2[reg];
                if (kc == 0)
                    v += (jj < C0_N) ? b0[c * C0_N + jj]
                                     : b1[c * C1_N + (jj - C0_N)];
                if (jj < C0_N)
                    atomicAdd(&out_c0[(size_t)row * C0_N + jj], v);
                else
                    atomicAdd(&out_c1[(size_t)row * C1_N + (jj - C0_N)], v);
            }
        }
    }
}

// ---------------------------------------------------------------------------
extern "C" void kernel_launch(void* const* d_in, const int* in_sizes, int n_in,
                              void* d_out, int out_size, void* d_ws, size_t ws_size,
                              hipStream_t stream) {
    const float* x  = (const float*)d_in[0];
    const float* pw = (const float*)d_in[1];
    const float* pb = (const float*)d_in[2];
    const float* w0 = (const float*)d_in[3];
    const float* b0 = (const float*)d_in[4];
    const float* w1 = (const float*)d_in[5];
    const float* b1 = (const float*)d_in[6];

    float* out_logits = (float*)d_out;                       // [4096][64]
    float* out_c0     = out_logits + (size_t)B_N * P_N;      // [4096][16]
    float* out_c1     = out_c0     + (size_t)B_N * C0_N;     // [4096][32]

    // ws: [pclass 4096 ints] — that's all.
    int* pclass = (int*)d_ws;

    hc_parent_fused<<<B_N / PRR, 256, 0, stream>>>(
        x, pw, pb, out_logits, out_c0, pclass);

    hc_child_mfma<<<dim3(P_N, KC2, 3), 256, 0, stream>>>(
        x, w0, w1, b0, b1, pclass, out_c0, out_c1);
}